// Round 8
// baseline (142.818 us; speedup 1.0000x reference)
//
#include <hip/hip_runtime.h>
#include <stdint.h>

// Bert4Argument: out[b,l,c] = sum_f feat[b,l,f] * W[c,f] + b[c]
// feat = [ seq[i, head[i,l], :] | pos_emb[l-pos[i]+256, :] | class_emb[(l==pos[i])?frame[i]:0, :] ]
// B=64, L=256, D=768 -> M=16384, K=2304, N=200 (padded to 16 tiles of 16)
//
// R8: drop the 80 MB bf16-mirror prep pass (was ~13 us). prep = W-pack only.
// GEMM stages A as RAW F32 via global_load_lds (DMA layout chosen so the
// wave-uniform-base + lane*16 constraint still yields fragment-readable LDS),
// converts f32->bf16 in registers after ds_read (VALU co-schedules with MFMA).
// LDS 64 KB (A 32 KB f32 + B 32 KB bf16) -> 2 blocks/CU, same R7 partition.
//
// A LDS layout, slab s = (mf*4+ks), 512 f32 each:
//   DMA (h in 0..1): lane l writes 16 B at s*512 + h*256 + l*4 from global
//     row (l&15), f32 offset ks*32 + (l>>4)*4 + h*16  -> element (r,kk) lives
//     at s*512 + (kk>>4)*256 + ((kk>>2)&3)*64 + r*4 + (kk&3).
//   Fragment read (quad,n16): kk = quad*8+j -> two contiguous f32x4 at
//     s*512 + (quad>>1)*256 + (quad&1)*128 + n16*4  (+64). Bank stride 16 B
//     -> 2-way aliasing only (free).

typedef __attribute__((ext_vector_type(8))) short short8;
typedef __attribute__((ext_vector_type(4))) float f32x4;

#define AS1 __attribute__((address_space(1)))
#define AS3 __attribute__((address_space(3)))

#define NW16_G 73728                        // 16*288*16 pack work-items
#define WP_NEED ((size_t)589824 * 2)        // 1,179,648 B packed W (16 tiles)
#define TILE_STRIDE 36864                   // 288*16*8 elems per packed n-tile

__device__ __forceinline__ unsigned short f2bf(float f) {
    union { float f; unsigned int u; } v; v.f = f;
    unsigned int u = v.u;
    return (unsigned short)((u + 0x7fffu + ((u >> 16) & 1u)) >> 16);
}

__device__ __forceinline__ short8 pack8(f32x4 a, f32x4 b) {
    short8 r;
    r[0] = (short)f2bf(a.x); r[1] = (short)f2bf(a.y);
    r[2] = (short)f2bf(a.z); r[3] = (short)f2bf(a.w);
    r[4] = (short)f2bf(b.x); r[5] = (short)f2bf(b.y);
    r[6] = (short)f2bf(b.z); r[7] = (short)f2bf(b.w);
    return r;
}

__device__ __forceinline__ void dma16(const unsigned short* g, AS3 unsigned short* l) {
    __builtin_amdgcn_global_load_lds((AS1 const unsigned int*)g,
                                     (AS3 unsigned int*)l, 16, 0, 0);
}
__device__ __forceinline__ void dma16f(const float* g, AS3 float* l) {
    __builtin_amdgcn_global_load_lds((AS1 const unsigned int*)g,
                                     (AS3 unsigned int*)l, 16, 0, 0);
}

// ---------------------------------------------------------------------------
// Prep: pack W f32 [200][2304] -> bf16 tiled, 16 n-tiles (rows >= 200 zero):
// Wp[((t*288+kb8)*16+n)*8+j] = W[t*16+n][kb8*8+j]
// ---------------------------------------------------------------------------
__global__ void cvt_w_kernel(const float* __restrict__ W,
                             unsigned short* __restrict__ Wp) {
    int g = blockIdx.x * 256 + threadIdx.x;
    if (g >= NW16_G) return;
    int n   = g & 15;
    int kb8 = (g >> 4) % 288;
    int t   = g / (288 * 16);
    int row = t * 16 + n;
    int col = kb8 * 8;
    f32x4 a = {0.f, 0.f, 0.f, 0.f}, b = {0.f, 0.f, 0.f, 0.f};
    if (row < 200) {
        const float* p = W + (size_t)row * 2304 + col;
        a = *(const f32x4*)p;
        b = *(const f32x4*)(p + 4);
    }
    *(short8*)(Wp + (size_t)g * 8) = pack8(a, b);
}

// ---------------------------------------------------------------------------
// GEMM: grid 512 x 512 thr. mblk = blockIdx&255 -> rows [64*mblk, +64),
// h = blockIdx>>8 -> n-tiles [8h, 8h+8). Batch i = mblk>>2. K-chunk = 128.
// ---------------------------------------------------------------------------
__global__ __launch_bounds__(512) void gemm7_kernel(
    const float* __restrict__ seq,   // [64,256,768] f32
    const float* __restrict__ pe,    // [513,768] f32
    const float* __restrict__ ce,    // [201,768] f32
    const float* __restrict__ bias,  // [200]
    const int*   __restrict__ head,  // [64,256]
    const int*   __restrict__ frame, // [64]
    const int*   __restrict__ pos,   // [64]
    const unsigned short* __restrict__ Wp,  // packed bf16 W (16 tiles)
    float* __restrict__ out)         // [16384,200]
{
    __shared__ float          ldsA[8192];    // 32 KB: 16 slabs x 512 f32
    __shared__ unsigned short ldsB[16384];   // 32 KB: 8 tiles x 2048 shorts

    const int tid  = threadIdx.x;
    const int wave = tid >> 6;
    const int lane = tid & 63;
    const int n16  = lane & 15;
    const int quad = lane >> 4;

    const int mblk = blockIdx.x & 255;
    const int h    = blockIdx.x >> 8;

    const int i       = mblk >> 2;
    const int pos_i   = pos[i];
    const int frame_i = frame[i];

    // ---- A staging: wave stages m-frag smf = wave&3, ks pair skb = (wave>>2)*2.
    //      Lane handles row n16 of that frag; per-lane f32 col = quad*4 (+h*16).
    const int smf = wave & 3;
    const int skb = (wave >> 2) * 2;
    const int srow = mblk * 64 + smf * 16 + n16;
    const float* aSt[3];
    {
        const int sj   = srow & 255;
        const int shi  = head[srow];
        const int srel = sj - pos_i + 256;                 // [1, 511]
        const int scls = (sj == pos_i) ? frame_i : 0;
        aSt[0] = seq + ((size_t)i * 256 + (size_t)shi) * 768 + quad * 4;
        aSt[1] = pe + (size_t)srel * 768 + quad * 4;
        aSt[2] = ce + (size_t)scls * 768 + quad * 4;
    }
    // A LDS dests: slab (smf, skb+e), half hh: base + lane*4
    AS3 float* aD[2][2];
#pragma unroll
    for (int e = 0; e < 2; ++e)
#pragma unroll
        for (int hh = 0; hh < 2; ++hh)
            aD[e][hh] = (AS3 float*)ldsA +
                        ((smf * 4 + skb + e) * 512 + hh * 256 + lane * 4);

    // ---- B staging: wave stages local tile `wave` (global tile h*8+wave) ----
    const unsigned short* bSt = Wp + (size_t)(h * 8 + wave) * TILE_STRIDE + lane * 8;
    AS3 unsigned short* bD = (AS3 unsigned short*)ldsB + wave * 2048 + lane * 8;

    // ---- compute partition: p = wave&1 -> m-frags {2p,2p+1};
    //      q = wave>>1 -> local tiles {q, q+4} ----
    const int p = wave & 1;
    const int q = wave >> 1;
    const int aoff = (quad >> 1) * 256 + (quad & 1) * 128 + n16 * 4;

    f32x4 acc[2][2];
#pragma unroll
    for (int u = 0; u < 2; ++u) {
        const int col = (h * 8 + q + 4 * u) * 16 + n16;
        const float bv = (col < 200) ? bias[col] : 0.0f;
        acc[0][u] = (f32x4){bv, bv, bv, bv};
        acc[1][u] = (f32x4){bv, bv, bv, bv};
    }

#pragma unroll
    for (int sg = 0; sg < 3; ++sg) {
        const float* aSrc = aSt[sg];
        const unsigned short* bSrc = bSt + (size_t)sg * 12288;  // 6 chunks * 2048
        for (int cc = 0; cc < 6; ++cc) {
            // stage chunk (128 k-values): 4 A-f32 dma16 + 4 B dma16 per wave
#pragma unroll
            for (int e = 0; e < 2; ++e)
#pragma unroll
                for (int hh = 0; hh < 2; ++hh)
                    dma16f(aSrc + cc * 128 + (skb + e) * 32 + hh * 16, aD[e][hh]);
#pragma unroll
            for (int r = 0; r < 4; ++r)
                dma16(bSrc + cc * 2048 + r * 512, bD + r * 512);
            __syncthreads();
            // compute: 4 ks x (2 A frag cvt + 2 B reads, 4 MFMA)
#pragma unroll
            for (int ks = 0; ks < 4; ++ks) {
                short8 af[2];
#pragma unroll
                for (int f = 0; f < 2; ++f) {
                    const float* ap = ldsA + ((2 * p + f) * 4 + ks) * 512 + aoff;
                    f32x4 v0 = *(const f32x4*)ap;
                    f32x4 v1 = *(const f32x4*)(ap + 64);
                    af[f] = pack8(v0, v1);
                }
#pragma unroll
                for (int u = 0; u < 2; ++u) {
                    short8 bf = *(const short8*)(ldsB + (q + 4 * u) * 2048 +
                                                 ks * 512 + quad * 128 + n16 * 8);
                    acc[0][u] = __builtin_amdgcn_mfma_f32_16x16x32_bf16(af[0], bf, acc[0][u], 0, 0, 0);
                    acc[1][u] = __builtin_amdgcn_mfma_f32_16x16x32_bf16(af[1], bf, acc[1][u], 0, 0, 0);
                }
            }
            __syncthreads();
        }
    }

    // epilogue: C/D layout col = lane&15, row = quad*4 + r
#pragma unroll
    for (int f = 0; f < 2; ++f) {
        const int rbase = mblk * 64 + (2 * p + f) * 16 + quad * 4;
#pragma unroll
        for (int u = 0; u < 2; ++u) {
            const int col = (h * 8 + q + 4 * u) * 16 + n16;
            if (col < 200) {
#pragma unroll
                for (int r = 0; r < 4; ++r)
                    out[(size_t)(rbase + r) * 200 + col] = acc[f][u][r];
            }
        }
    }
}

// ---------------------------------------------------------------------------
// Fallback (no workspace): slow but correct, f32 W converted inline.
// ---------------------------------------------------------------------------
__global__ __launch_bounds__(256) void gemm_fallback(
    const float* __restrict__ seq, const float* __restrict__ pe,
    const float* __restrict__ ce, const float* __restrict__ Wf,
    const float* __restrict__ bias, const int* __restrict__ head,
    const int* __restrict__ frame, const int* __restrict__ pos,
    float* __restrict__ out)
{
    const int tid  = threadIdx.x;
    const int wave = tid >> 6;
    const int lane = tid & 63;
    const int n16  = lane & 15;
    const int quad = lane >> 4;

    const int mrow  = blockIdx.x * 16 + n16;
    const int i     = mrow >> 8;
    const int j     = mrow & 255;
    const int pos_i = pos[i];
    const int hi    = head[mrow];
    const int rel   = j - pos_i + 256;
    const int cls   = (j == pos_i) ? frame[i] : 0;

    const float* segs[3];
    segs[0] = seq + ((size_t)i * 256 + (size_t)hi) * 768 + quad * 8;
    segs[1] = pe + (size_t)rel * 768 + quad * 8;
    segs[2] = ce + (size_t)cls * 768 + quad * 8;

    const int ntl = (wave == 0) ? 4 : 3;
    f32x4 acc[4];
#pragma unroll
    for (int u = 0; u < 4; ++u) {
        const int t = wave + 4 * u;
        const int col = t * 16 + n16;
        const float bv = (t < 13 && col < 200) ? bias[col] : 0.0f;
        acc[u] = (f32x4){bv, bv, bv, bv};
    }

    for (int s = 0; s < 3; ++s) {
        const float* ap = segs[s];
#pragma unroll 2
        for (int kk = 0; kk < 768; kk += 32) {
            short8 afr = pack8(*(const f32x4*)(ap + kk), *(const f32x4*)(ap + kk + 4));
#pragma unroll
            for (int u = 0; u < 4; ++u) {
                if (u < ntl) {
                    const int t = wave + 4 * u;
                    const int row = t * 16 + n16;
                    short8 bfr = {0, 0, 0, 0, 0, 0, 0, 0};
                    if (row < 200) {
                        const float* qp = Wf + (size_t)row * 2304 + s * 768 + kk + quad * 8;
                        bfr = pack8(*(const f32x4*)qp, *(const f32x4*)(qp + 4));
                    }
                    acc[u] = __builtin_amdgcn_mfma_f32_16x16x32_bf16(afr, bfr, acc[u], 0, 0, 0);
                }
            }
        }
    }

    const int rbase = blockIdx.x * 16 + quad * 4;
#pragma unroll
    for (int u = 0; u < 4; ++u) {
        const int t = wave + 4 * u;
        if (t < 13) {
            const int col = t * 16 + n16;
            if (col < 200) {
#pragma unroll
                for (int r = 0; r < 4; ++r)
                    out[(size_t)(rbase + r) * 200 + col] = acc[u][r];
            }
        }
    }
}

// ---------------------------------------------------------------------------
extern "C" void kernel_launch(void* const* d_in, const int* in_sizes, int n_in,
                              void* d_out, int out_size, void* d_ws, size_t ws_size,
                              hipStream_t stream) {
    const float* seq  = (const float*)d_in[0];
    const float* pe   = (const float*)d_in[1];
    const float* ce   = (const float*)d_in[2];
    const float* W    = (const float*)d_in[3];
    const float* bias = (const float*)d_in[4];
    const int* head   = (const int*)d_in[5];
    const int* frame  = (const int*)d_in[6];
    const int* pos    = (const int*)d_in[7];
    float* out = (float*)d_out;

    if (d_ws != nullptr && ws_size >= WP_NEED) {
        unsigned short* Wp = (unsigned short*)d_ws;
        cvt_w_kernel<<<(NW16_G + 255) / 256, 256, 0, stream>>>(W, Wp);
        gemm7_kernel<<<512, 512, 0, stream>>>(seq, pe, ce, bias, head, frame,
                                              pos, Wp, out);
    } else {
        gemm_fallback<<<1024, 256, 0, stream>>>(seq, pe, ce, W, bias, head,
                                                frame, pos, out);
    }
}

// Round 9
// 142.021 us; speedup vs baseline: 1.0056x; 1.0056x over previous
//
#include <hip/hip_runtime.h>
#include <stdint.h>

// Bert4Argument: out[b,l,c] = sum_f feat[b,l,f] * W[c,f] + b[c]
// feat = [ seq[i, head[i,l], :] | pos_emb[l-pos[i]+256, :] | class_emb[(l==pos[i])?frame[i]:0, :] ]
// B=64, L=256, D=768 -> M=16384, K=2304, N=200 (padded to 16 tiles of 16)
//
// R9 = R7 compute structure (all-bf16 LDS, global_load_lds for B, 2 barriers,
// 2 blocks/CU) but WITHOUT the 106 MB mirror prep pass:
//  - prep = W-pack only (~3 MB traffic).
//  - A staged by per-lane f32 global loads + ONE pack8 + ds_write_b128 into
//    the same fragment-ordered bf16 LDS layout (convert once per value, in
//    the staging phase -- not per consumer like R8's failed in-loop cvt).
// LDS 48 KB (A 16 KB bf16 + B 32 KB bf16) -> 2 blocks/CU.

typedef __attribute__((ext_vector_type(8))) short short8;
typedef __attribute__((ext_vector_type(4))) float f32x4;

#define AS1 __attribute__((address_space(1)))
#define AS3 __attribute__((address_space(3)))

#define NW16_G 73728                        // 16*288*16 pack work-items
#define WP_NEED ((size_t)589824 * 2)        // 1,179,648 B packed W (16 tiles)
#define TILE_STRIDE 36864                   // 288*16*8 elems per packed n-tile

__device__ __forceinline__ unsigned short f2bf(float f) {
    union { float f; unsigned int u; } v; v.f = f;
    unsigned int u = v.u;
    return (unsigned short)((u + 0x7fffu + ((u >> 16) & 1u)) >> 16);
}

__device__ __forceinline__ short8 pack8(f32x4 a, f32x4 b) {
    short8 r;
    r[0] = (short)f2bf(a.x); r[1] = (short)f2bf(a.y);
    r[2] = (short)f2bf(a.z); r[3] = (short)f2bf(a.w);
    r[4] = (short)f2bf(b.x); r[5] = (short)f2bf(b.y);
    r[6] = (short)f2bf(b.z); r[7] = (short)f2bf(b.w);
    return r;
}

__device__ __forceinline__ void dma16(const unsigned short* g, AS3 unsigned short* l) {
    __builtin_amdgcn_global_load_lds((AS1 const unsigned int*)g,
                                     (AS3 unsigned int*)l, 16, 0, 0);
}

// ---------------------------------------------------------------------------
// Prep: pack W f32 [200][2304] -> bf16 tiled, 16 n-tiles (rows >= 200 zero):
// Wp[((t*288+kb8)*16+n)*8+j] = W[t*16+n][kb8*8+j]
// ---------------------------------------------------------------------------
__global__ void cvt_w_kernel(const float* __restrict__ W,
                             unsigned short* __restrict__ Wp) {
    int g = blockIdx.x * 256 + threadIdx.x;
    if (g >= NW16_G) return;
    int n   = g & 15;
    int kb8 = (g >> 4) % 288;
    int t   = g / (288 * 16);
    int row = t * 16 + n;
    int col = kb8 * 8;
    f32x4 a = {0.f, 0.f, 0.f, 0.f}, b = {0.f, 0.f, 0.f, 0.f};
    if (row < 200) {
        const float* p = W + (size_t)row * 2304 + col;
        a = *(const f32x4*)p;
        b = *(const f32x4*)(p + 4);
    }
    *(short8*)(Wp + (size_t)g * 8) = pack8(a, b);
}

// ---------------------------------------------------------------------------
// GEMM: grid 512 x 512 thr. mblk = blockIdx&255 -> rows [64*mblk, +64),
// h = blockIdx>>8 -> n-tiles [8h, 8h+8). Batch i = mblk>>2. K-chunk = 128.
// LDS: A = 16 slabs (fm 0..3, ks 0..3) x 512 shorts, addr ((fm*4+ks)*64+lane)*8
//      (lane=(quad,n16): row n16, k = ks*32 + quad*8 + j)
//      B = 8 local tiles x 2048 shorts at +8192.
// Staging per chunk per wave: 4 B dma16 (tile=wave); A: fm=w&3, ks pair
// skb=(w>>2)*2 -- per lane 4 f32x4 global loads, 2 pack8, 2 ds_write_b128.
// Compute (as R7): p=w&1 -> m-frags {2p,2p+1}; q=w>>1 -> tiles {q,q+4};
// 4 ks x (2 A + 2 B ds_read_b128, 4 MFMA).
// ---------------------------------------------------------------------------
__global__ __launch_bounds__(512) void gemm8_kernel(
    const float* __restrict__ seq,   // [64,256,768] f32
    const float* __restrict__ pe,    // [513,768] f32
    const float* __restrict__ ce,    // [201,768] f32
    const float* __restrict__ bias,  // [200]
    const int*   __restrict__ head,  // [64,256]
    const int*   __restrict__ frame, // [64]
    const int*   __restrict__ pos,   // [64]
    const unsigned short* __restrict__ Wp,  // packed bf16 W (16 tiles)
    float* __restrict__ out)         // [16384,200]
{
    __shared__ unsigned short lds[8192 + 16384];   // 48 KB: A bf16 | B bf16

    const int tid  = threadIdx.x;
    const int wave = tid >> 6;
    const int lane = tid & 63;
    const int n16  = lane & 15;
    const int quad = lane >> 4;

    const int mblk = blockIdx.x & 255;
    const int h    = blockIdx.x >> 8;

    const int i       = mblk >> 2;
    const int pos_i   = pos[i];
    const int frame_i = frame[i];

    // ---- A staging: wave stages m-frag smf = wave&3, ks pair skb = (wave>>2)*2.
    //      Lane (quad,n16): row n16 of frag smf, f32 cols (skb+e)*32 + quad*8.
    const int smf = wave & 3;
    const int skb = (wave >> 2) * 2;
    const int skb32 = skb * 32;
    const int srow = mblk * 64 + smf * 16 + n16;
    const float* aSt[3];
    {
        const int sj   = srow & 255;
        const int shi  = head[srow];
        const int srel = sj - pos_i + 256;                 // [1, 511]
        const int scls = (sj == pos_i) ? frame_i : 0;
        aSt[0] = seq + ((size_t)i * 256 + (size_t)shi) * 768 + quad * 8;
        aSt[1] = pe + (size_t)srel * 768 + quad * 8;
        aSt[2] = ce + (size_t)scls * 768 + quad * 8;
    }
    unsigned short* aW0 = lds + ((smf * 4 + skb + 0) * 64 + lane) * 8;
    unsigned short* aW1 = lds + ((smf * 4 + skb + 1) * 64 + lane) * 8;

    // ---- B staging: wave stages local tile `wave` (global tile h*8+wave) ----
    const unsigned short* bSt = Wp + (size_t)(h * 8 + wave) * TILE_STRIDE + lane * 8;
    AS3 unsigned short* bD = (AS3 unsigned short*)lds + 8192 + wave * 2048 + lane * 8;

    // ---- compute partition ----
    const int p = wave & 1;
    const int q = wave >> 1;

    const unsigned short* aRd[2];   // + ks*512
    const unsigned short* bRd[2];   // + ks*512
#pragma unroll
    for (int f = 0; f < 2; ++f)
        aRd[f] = lds + (2 * p + f) * 2048 + lane * 8;
#pragma unroll
    for (int u = 0; u < 2; ++u)
        bRd[u] = lds + 8192 + (q + 4 * u) * 2048 + quad * 128 + n16 * 8;

    f32x4 acc[2][2];
#pragma unroll
    for (int u = 0; u < 2; ++u) {
        const int col = (h * 8 + q + 4 * u) * 16 + n16;
        const float bv = (col < 200) ? bias[col] : 0.0f;
        acc[0][u] = (f32x4){bv, bv, bv, bv};
        acc[1][u] = (f32x4){bv, bv, bv, bv};
    }

#pragma unroll
    for (int sg = 0; sg < 3; ++sg) {
        const float* aSrc = aSt[sg];
        const unsigned short* bSrc = bSt + (size_t)sg * 12288;  // 6 chunks * 2048
        for (int cc = 0; cc < 6; ++cc) {
            // B: 4 async DMAs (issued first, drain during A load/convert)
#pragma unroll
            for (int r = 0; r < 4; ++r)
                dma16(bSrc + cc * 2048 + r * 512, bD + r * 512);
            // A: per-lane f32 loads for the wave's two slabs, convert once,
            // write fragment-ordered bf16 to LDS.
            {
                const float* ap = aSrc + cc * 128 + skb32;
                f32x4 v00 = *(const f32x4*)(ap);
                f32x4 v01 = *(const f32x4*)(ap + 4);
                f32x4 v10 = *(const f32x4*)(ap + 32);
                f32x4 v11 = *(const f32x4*)(ap + 36);
                *(short8*)aW0 = pack8(v00, v01);
                *(short8*)aW1 = pack8(v10, v11);
            }
            __syncthreads();
            // compute: 4 ks x (2 A + 2 B reads, 4 MFMA)
#pragma unroll
            for (int ks = 0; ks < 4; ++ks) {
                short8 a0 = *(const short8*)(aRd[0] + ks * 512);
                short8 a1 = *(const short8*)(aRd[1] + ks * 512);
#pragma unroll
                for (int u = 0; u < 2; ++u) {
                    short8 bf = *(const short8*)(bRd[u] + ks * 512);
                    acc[0][u] = __builtin_amdgcn_mfma_f32_16x16x32_bf16(a0, bf, acc[0][u], 0, 0, 0);
                    acc[1][u] = __builtin_amdgcn_mfma_f32_16x16x32_bf16(a1, bf, acc[1][u], 0, 0, 0);
                }
            }
            __syncthreads();
        }
    }

    // epilogue: C/D layout col = lane&15, row = quad*4 + r
#pragma unroll
    for (int f = 0; f < 2; ++f) {
        const int rbase = mblk * 64 + (2 * p + f) * 16 + quad * 4;
#pragma unroll
        for (int u = 0; u < 2; ++u) {
            const int col = (h * 8 + q + 4 * u) * 16 + n16;
            if (col < 200) {
#pragma unroll
                for (int r = 0; r < 4; ++r)
                    out[(size_t)(rbase + r) * 200 + col] = acc[f][u][r];
            }
        }
    }
}

// ---------------------------------------------------------------------------
// Fallback (no workspace): slow but correct, f32 W converted inline.
// ---------------------------------------------------------------------------
__global__ __launch_bounds__(256) void gemm_fallback(
    const float* __restrict__ seq, const float* __restrict__ pe,
    const float* __restrict__ ce, const float* __restrict__ Wf,
    const float* __restrict__ bias, const int* __restrict__ head,
    const int* __restrict__ frame, const int* __restrict__ pos,
    float* __restrict__ out)
{
    const int tid  = threadIdx.x;
    const int wave = tid >> 6;
    const int lane = tid & 63;
    const int n16  = lane & 15;
    const int quad = lane >> 4;

    const int mrow  = blockIdx.x * 16 + n16;
    const int i     = mrow >> 8;
    const int j     = mrow & 255;
    const int pos_i = pos[i];
    const int hi    = head[mrow];
    const int rel   = j - pos_i + 256;
    const int cls   = (j == pos_i) ? frame[i] : 0;

    const float* segs[3];
    segs[0] = seq + ((size_t)i * 256 + (size_t)hi) * 768 + quad * 8;
    segs[1] = pe + (size_t)rel * 768 + quad * 8;
    segs[2] = ce + (size_t)cls * 768 + quad * 8;

    const int ntl = (wave == 0) ? 4 : 3;
    f32x4 acc[4];
#pragma unroll
    for (int u = 0; u < 4; ++u) {
        const int t = wave + 4 * u;
        const int col = t * 16 + n16;
        const float bv = (t < 13 && col < 200) ? bias[col] : 0.0f;
        acc[u] = (f32x4){bv, bv, bv, bv};
    }

    for (int s = 0; s < 3; ++s) {
        const float* ap = segs[s];
#pragma unroll 2
        for (int kk = 0; kk < 768; kk += 32) {
            short8 afr = pack8(*(const f32x4*)(ap + kk), *(const f32x4*)(ap + kk + 4));
#pragma unroll
            for (int u = 0; u < 4; ++u) {
                if (u < ntl) {
                    const int t = wave + 4 * u;
                    const int row = t * 16 + n16;
                    short8 bfr = {0, 0, 0, 0, 0, 0, 0, 0};
                    if (row < 200) {
                        const float* qp = Wf + (size_t)row * 2304 + s * 768 + kk + quad * 8;
                        bfr = pack8(*(const f32x4*)qp, *(const f32x4*)(qp + 4));
                    }
                    acc[u] = __builtin_amdgcn_mfma_f32_16x16x32_bf16(afr, bfr, acc[u], 0, 0, 0);
                }
            }
        }
    }

    const int rbase = blockIdx.x * 16 + quad * 4;
#pragma unroll
    for (int u = 0; u < 4; ++u) {
        const int t = wave + 4 * u;
        if (t < 13) {
            const int col = t * 16 + n16;
            if (col < 200) {
#pragma unroll
                for (int r = 0; r < 4; ++r)
                    out[(size_t)(rbase + r) * 200 + col] = acc[u][r];
            }
        }
    }
}

// ---------------------------------------------------------------------------
extern "C" void kernel_launch(void* const* d_in, const int* in_sizes, int n_in,
                              void* d_out, int out_size, void* d_ws, size_t ws_size,
                              hipStream_t stream) {
    const float* seq  = (const float*)d_in[0];
    const float* pe   = (const float*)d_in[1];
    const float* ce   = (const float*)d_in[2];
    const float* W    = (const float*)d_in[3];
    const float* bias = (const float*)d_in[4];
    const int* head   = (const int*)d_in[5];
    const int* frame  = (const int*)d_in[6];
    const int* pos    = (const int*)d_in[7];
    float* out = (float*)d_out;

    if (d_ws != nullptr && ws_size >= WP_NEED) {
        unsigned short* Wp = (unsigned short*)d_ws;
        cvt_w_kernel<<<(NW16_G + 255) / 256, 256, 0, stream>>>(W, Wp);
        gemm8_kernel<<<512, 512, 0, stream>>>(seq, pe, ce, bias, head, frame,
                                              pos, Wp, out);
    } else {
        gemm_fallback<<<1024, 256, 0, stream>>>(seq, pe, ce, W, bias, head,
                                                frame, pos, out);
    }
}

// Round 10
// 134.504 us; speedup vs baseline: 1.0618x; 1.0559x over previous
//
#include <hip/hip_runtime.h>
#include <stdint.h>

// Bert4Argument: out[b,l,c] = sum_f feat[b,l,f] * W[c,f] + b[c]
// feat = [ seq[i, head[i,l], :] | pos_emb[l-pos[i]+256, :] | class_emb[(l==pos[i])?frame[i]:0, :] ]
// B=64, L=256, D=768 -> M=16384, K=2304, N=200 (padded to 16 tiles of 16)
//
// R10: all-DMA staging (R7) + double-buffered LDS with ONE barrier per chunk
// + high-reuse partition.
//  - prep: bf16 mirrors of seq/pe/ce + packed 16-tile W (zero VALU in hot loop).
//  - gemm: grid 256 (1 block/CU), 512 thr / 8 waves, block = 64 rows x ALL 16
//    n-tiles. Wave computes 2 m-frags x 4 tiles: per 32-k step 6 ds_read_b128
//    -> 8 MFMAs (was 1:1). K-chunk = 64.
//  - dbuf: stage chunk c+1 into buf[(c+1)&1] via global_load_lds, THEN compute
//    chunk c from buf[c&1], then __syncthreads. The barrier's vmcnt(0) drain
//    waits on DMAs that already aged one full compute phase -> hidden in-block.
//  - LDS 2 x 40 KB = 80 KB, 1 block/CU.

typedef __attribute__((ext_vector_type(8))) short short8;
typedef __attribute__((ext_vector_type(4))) float f32x4;

#define AS1 __attribute__((address_space(1)))
#define AS3 __attribute__((address_space(3)))

#define NSEQ_G 1572864   // 64*256*768/8
#define NPE_G  49248     // 513*768/8
#define NCE_G  19296     // 201*768/8
#define NW16_G 73728     // 16*288*16
#define SEQB_OFF 0
#define PEB_OFF  12582912
#define CEB_OFF  (PEB_OFF + 393984)     // 12,976,896
#define WP_OFF   (CEB_OFF + 154368)     // 13,131,264
#define WS_ELEMS (WP_OFF + 589824)      // 13,721,088
#define WS_NEED  ((size_t)WS_ELEMS * 2) // 27,442,176 B
#define TILE_STRIDE 36864               // 288*16*8 elems per packed n-tile
#define BUFS 20480                      // shorts per LDS buffer: A 4096 + B 16384

__device__ __forceinline__ unsigned short f2bf(float f) {
    union { float f; unsigned int u; } v; v.f = f;
    unsigned int u = v.u;
    return (unsigned short)((u + 0x7fffu + ((u >> 16) & 1u)) >> 16);
}

__device__ __forceinline__ short8 pack8(f32x4 a, f32x4 b) {
    short8 r;
    r[0] = (short)f2bf(a.x); r[1] = (short)f2bf(a.y);
    r[2] = (short)f2bf(a.z); r[3] = (short)f2bf(a.w);
    r[4] = (short)f2bf(b.x); r[5] = (short)f2bf(b.y);
    r[6] = (short)f2bf(b.z); r[7] = (short)f2bf(b.w);
    return r;
}

__device__ __forceinline__ void dma16(const unsigned short* g, AS3 unsigned short* l) {
    __builtin_amdgcn_global_load_lds((AS1 const unsigned int*)g,
                                     (AS3 unsigned int*)l, 16, 0, 0);
}

// ---------------------------------------------------------------------------
// Prep: bf16 mirrors of seq/pe/ce; pack W f32 [200][2304] -> bf16 tiled with
// 16 n-tiles (rows >= 200 zero): Wp[((t*288+kb8)*16+n)*8+j] = W[t*16+n][kb8*8+j]
// ---------------------------------------------------------------------------
__global__ void prep_kernel(const float* __restrict__ seq,
                            const float* __restrict__ pe,
                            const float* __restrict__ ce,
                            const float* __restrict__ W,
                            unsigned short* __restrict__ ws) {
    int g = blockIdx.x * 256 + threadIdx.x;
    if (g < NSEQ_G) {
        const float* p = seq + (size_t)g * 8;
        *(short8*)(ws + SEQB_OFF + (size_t)g * 8) =
            pack8(*(const f32x4*)p, *(const f32x4*)(p + 4));
        return;
    }
    g -= NSEQ_G;
    if (g < NPE_G) {
        const float* p = pe + (size_t)g * 8;
        *(short8*)(ws + PEB_OFF + (size_t)g * 8) =
            pack8(*(const f32x4*)p, *(const f32x4*)(p + 4));
        return;
    }
    g -= NPE_G;
    if (g < NCE_G) {
        const float* p = ce + (size_t)g * 8;
        *(short8*)(ws + CEB_OFF + (size_t)g * 8) =
            pack8(*(const f32x4*)p, *(const f32x4*)(p + 4));
        return;
    }
    g -= NCE_G;
    if (g < NW16_G) {
        int n   = g & 15;
        int kb8 = (g >> 4) % 288;
        int t   = g / (288 * 16);
        int row = t * 16 + n;
        int col = kb8 * 8;
        f32x4 a = {0.f, 0.f, 0.f, 0.f}, b = {0.f, 0.f, 0.f, 0.f};
        if (row < 200) {
            const float* p = W + (size_t)row * 2304 + col;
            a = *(const f32x4*)p;
            b = *(const f32x4*)(p + 4);
        }
        *(short8*)(ws + WP_OFF + (size_t)g * 8) = pack8(a, b);
    }
}

// ---------------------------------------------------------------------------
// GEMM: grid 256 x 512 thr. Block = rows [64b, 64b+64) x all 16 n-tiles.
// Batch i = b>>2. K-chunk = 64 (36 chunks).
// LDS buffer (20480 shorts): A = 8 slabs (slab s = mf*2+ks) x 512 shorts,
//   slab addr (s*64+lane)*8, lane=(quad,n16) holds row n16, k=ks*32+quad*8+j.
//   B at +4096: tile t x 1024 shorts; frag addr t*1024 + (ks*4+quad)*128 + n16*8.
// Staging per wave per chunk: A slab `wave` (1 dma16), B tiles {2w,2w+1}
//   (4 dma16). Compute: p=w&1 -> m-frags {2p,2p+1}; q=w>>1 -> tiles
//   {q,q+4,q+8,q+12}; 2 ks x (2 A + 4 B reads -> 8 MFMAs).
// ---------------------------------------------------------------------------
__global__ __launch_bounds__(512) void gemm9_kernel(
    const unsigned short* __restrict__ ws,
    const float* __restrict__ bias,
    const int*   __restrict__ head,
    const int*   __restrict__ frame,
    const int*   __restrict__ pos,
    float* __restrict__ out)
{
    __shared__ unsigned short lds[2 * BUFS];   // 80 KB

    const unsigned short* seqb = ws + SEQB_OFF;
    const unsigned short* peb  = ws + PEB_OFF;
    const unsigned short* ceb  = ws + CEB_OFF;
    const unsigned short* Wp   = ws + WP_OFF;

    const int tid  = threadIdx.x;
    const int wave = tid >> 6;
    const int lane = tid & 63;
    const int n16  = lane & 15;
    const int quad = lane >> 4;

    const int mblk = blockIdx.x;
    const int i       = mblk >> 2;
    const int pos_i   = pos[i];
    const int frame_i = frame[i];

    // ---- A staging: wave stages slab `wave` (mf = wave>>1, ks = wave&1) ----
    const int smf = wave >> 1;
    const int sks = wave & 1;
    const int srow = mblk * 64 + smf * 16 + n16;
    const unsigned short *aSt0, *aSt1, *aSt2;
    {
        const int sj   = srow & 255;
        const int shi  = head[srow];
        const int srel = sj - pos_i + 256;                 // [1, 511]
        const int scls = (sj == pos_i) ? frame_i : 0;
        const int loff = sks * 32 + quad * 8;
        aSt0 = seqb + ((size_t)i * 256 + (size_t)shi) * 768 + loff;
        aSt1 = peb + (size_t)srel * 768 + loff;
        aSt2 = ceb + (size_t)scls * 768 + loff;
    }
    // ---- B staging: wave stages tiles {2w, 2w+1}; chunk c at offset c*1024 ----
    const unsigned short* bSt0 = Wp + (size_t)(2 * wave) * TILE_STRIDE + lane * 8;
    const unsigned short* bSt1 = bSt0 + TILE_STRIDE;

    AS3 unsigned short* ldsw = (AS3 unsigned short*)lds;
    const int aDstOff = (wave * 64 + lane) * 8;
    const int bDstOff = 4096 + wave * 2048 + lane * 8;

    // ---- compute partition ----
    const int p = wave & 1;
    const int q = wave >> 1;

    f32x4 acc[2][4];
#pragma unroll
    for (int u = 0; u < 4; ++u) {
        const int col = (q + 4 * u) * 16 + n16;
        const float bv = (col < 200) ? bias[col] : 0.0f;
        acc[0][u] = (f32x4){bv, bv, bv, bv};
        acc[1][u] = (f32x4){bv, bv, bv, bv};
    }

    const int aRd0 = ((2 * p + 0) * 2) * 512 + lane * 8;   // + ks*512
    const int aRd1 = ((2 * p + 1) * 2) * 512 + lane * 8;
    const int bRdB = 4096 + q * 1024 + quad * 128 + n16 * 8; // + u*4096 + ks*512

    auto stage = [&](int c, int b) {
        const unsigned short* ap;
        int cc;
        if (c < 12)      { ap = aSt0; cc = c; }
        else if (c < 24) { ap = aSt1; cc = c - 12; }
        else             { ap = aSt2; cc = c - 24; }
        AS3 unsigned short* base = ldsw + b * BUFS;
        dma16(ap + cc * 64, base + aDstOff);
        const int co = c * 1024;
        dma16(bSt0 + co,       base + bDstOff);
        dma16(bSt0 + co + 512, base + bDstOff + 512);
        dma16(bSt1 + co,       base + bDstOff + 1024);
        dma16(bSt1 + co + 512, base + bDstOff + 1536);
    };

    auto compute = [&](int c) {
        const unsigned short* base = lds + (c & 1) * BUFS;
#pragma unroll
        for (int ks = 0; ks < 2; ++ks) {
            short8 a0 = *(const short8*)(base + aRd0 + ks * 512);
            short8 a1 = *(const short8*)(base + aRd1 + ks * 512);
#pragma unroll
            for (int u = 0; u < 4; ++u) {
                short8 bf = *(const short8*)(base + bRdB + u * 4096 + ks * 512);
                acc[0][u] = __builtin_amdgcn_mfma_f32_16x16x32_bf16(a0, bf, acc[0][u], 0, 0, 0);
                acc[1][u] = __builtin_amdgcn_mfma_f32_16x16x32_bf16(a1, bf, acc[1][u], 0, 0, 0);
            }
        }
    };

    stage(0, 0);
    __syncthreads();
    for (int c = 0; c < 35; ++c) {
        stage(c + 1, (c + 1) & 1);
        compute(c);
        __syncthreads();
    }
    compute(35);

    // epilogue: C/D layout col = lane&15, row = quad*4 + r
#pragma unroll
    for (int f = 0; f < 2; ++f) {
        const int rbase = mblk * 64 + (2 * p + f) * 16 + quad * 4;
#pragma unroll
        for (int u = 0; u < 4; ++u) {
            const int col = (q + 4 * u) * 16 + n16;
            if (col < 200) {
#pragma unroll
                for (int r = 0; r < 4; ++r)
                    out[(size_t)(rbase + r) * 200 + col] = acc[f][u][r];
            }
        }
    }
}

// ---------------------------------------------------------------------------
// Fallback (no workspace): slow but correct, f32 W converted inline.
// ---------------------------------------------------------------------------
__global__ __launch_bounds__(256) void gemm_fallback(
    const float* __restrict__ seq, const float* __restrict__ pe,
    const float* __restrict__ ce, const float* __restrict__ Wf,
    const float* __restrict__ bias, const int* __restrict__ head,
    const int* __restrict__ frame, const int* __restrict__ pos,
    float* __restrict__ out)
{
    const int tid  = threadIdx.x;
    const int wave = tid >> 6;
    const int lane = tid & 63;
    const int n16  = lane & 15;
    const int quad = lane >> 4;

    const int mrow  = blockIdx.x * 16 + n16;
    const int i     = mrow >> 8;
    const int j     = mrow & 255;
    const int pos_i = pos[i];
    const int hi    = head[mrow];
    const int rel   = j - pos_i + 256;
    const int cls   = (j == pos_i) ? frame[i] : 0;

    const float* segs[3];
    segs[0] = seq + ((size_t)i * 256 + (size_t)hi) * 768 + quad * 8;
    segs[1] = pe + (size_t)rel * 768 + quad * 8;
    segs[2] = ce + (size_t)cls * 768 + quad * 8;

    const int ntl = (wave == 0) ? 4 : 3;
    f32x4 acc[4];
#pragma unroll
    for (int u = 0; u < 4; ++u) {
        const int t = wave + 4 * u;
        const int col = t * 16 + n16;
        const float bv = (t < 13 && col < 200) ? bias[col] : 0.0f;
        acc[u] = (f32x4){bv, bv, bv, bv};
    }

    for (int s = 0; s < 3; ++s) {
        const float* ap = segs[s];
#pragma unroll 2
        for (int kk = 0; kk < 768; kk += 32) {
            short8 afr = pack8(*(const f32x4*)(ap + kk), *(const f32x4*)(ap + kk + 4));
#pragma unroll
            for (int u = 0; u < 4; ++u) {
                if (u < ntl) {
                    const int t = wave + 4 * u;
                    const int row = t * 16 + n16;
                    short8 bfr = {0, 0, 0, 0, 0, 0, 0, 0};
                    if (row < 200) {
                        const float* qp = Wf + (size_t)row * 2304 + s * 768 + kk + quad * 8;
                        bfr = pack8(*(const f32x4*)qp, *(const f32x4*)(qp + 4));
                    }
                    acc[u] = __builtin_amdgcn_mfma_f32_16x16x32_bf16(afr, bfr, acc[u], 0, 0, 0);
                }
            }
        }
    }

    const int rbase = blockIdx.x * 16 + quad * 4;
#pragma unroll
    for (int u = 0; u < 4; ++u) {
        const int t = wave + 4 * u;
        if (t < 13) {
            const int col = t * 16 + n16;
            if (col < 200) {
#pragma unroll
                for (int r = 0; r < 4; ++r)
                    out[(size_t)(rbase + r) * 200 + col] = acc[u][r];
            }
        }
    }
}

// ---------------------------------------------------------------------------
extern "C" void kernel_launch(void* const* d_in, const int* in_sizes, int n_in,
                              void* d_out, int out_size, void* d_ws, size_t ws_size,
                              hipStream_t stream) {
    const float* seq  = (const float*)d_in[0];
    const float* pe   = (const float*)d_in[1];
    const float* ce   = (const float*)d_in[2];
    const float* W    = (const float*)d_in[3];
    const float* bias = (const float*)d_in[4];
    const int* head   = (const int*)d_in[5];
    const int* frame  = (const int*)d_in[6];
    const int* pos    = (const int*)d_in[7];
    float* out = (float*)d_out;

    if (d_ws != nullptr && ws_size >= WS_NEED) {
        unsigned short* ws = (unsigned short*)d_ws;
        const int total_g = NSEQ_G + NPE_G + NCE_G + NW16_G;   // 1,715,136
        prep_kernel<<<(total_g + 255) / 256, 256, 0, stream>>>(seq, pe, ce, W, ws);
        gemm9_kernel<<<256, 512, 0, stream>>>(ws, bias, head, frame, pos, out);
    } else {
        gemm_fallback<<<1024, 256, 0, stream>>>(seq, pe, ce, W, bias, head,
                                                frame, pos, out);
    }
}